// Round 1
// baseline (474.456 us; speedup 1.0000x reference)
//
#include <hip/hip_runtime.h>
#include <hip/hip_bf16.h>

#define NR 4096
#define DIM 1024
#define NCLS 512

typedef __attribute__((ext_vector_type(4))) float f32x4;
typedef __attribute__((ext_vector_type(8))) short bf16x8;

static __device__ __forceinline__ unsigned short f2bf(float f) {
  __hip_bfloat16 h = __float2bfloat16(f);
  return *reinterpret_cast<unsigned short*>(&h);
}

// ---------------- kernel 1: row norms + bf16 normalized copy ----------------
__global__ __launch_bounds__(256) void k_norm(const float* __restrict__ x,
                                              unsigned short* __restrict__ xn,
                                              float* __restrict__ norms) {
  int row = blockIdx.x * 4 + (threadIdx.x >> 6);
  int lane = threadIdx.x & 63;
  const float4* xr = reinterpret_cast<const float4*>(x + (size_t)row * DIM);
  float4 v[4];
  float s = 0.f;
#pragma unroll
  for (int it = 0; it < 4; ++it) {
    v[it] = xr[it * 64 + lane];
    s += v[it].x * v[it].x + v[it].y * v[it].y + v[it].z * v[it].z + v[it].w * v[it].w;
  }
#pragma unroll
  for (int d = 1; d < 64; d <<= 1) s += __shfl_xor(s, d);
  float nrm = fmaxf(sqrtf(s), 1e-8f);
  float inv = 1.0f / nrm;
  if (lane == 0) norms[row] = nrm;
  ushort4* xo = reinterpret_cast<ushort4*>(xn + (size_t)row * DIM);
#pragma unroll
  for (int it = 0; it < 4; ++it) {
    ushort4 u;
    u.x = f2bf(v[it].x * inv);
    u.y = f2bf(v[it].y * inv);
    u.z = f2bf(v[it].z * inv);
    u.w = f2bf(v[it].w * inv);
    xo[it * 64 + lane] = u;
  }
}

// ---------------- kernel 2: label histogram + first positive ----------------
__global__ __launch_bounds__(256) void k_labels(const int* __restrict__ y,
                                                int* __restrict__ cnt,
                                                int* __restrict__ fpos) {
  __shared__ int ys[NR];
  int tid = threadIdx.x;
  for (int j = tid; j < NR; j += 256) ys[j] = y[j];
  __syncthreads();
  int i = blockIdx.x * 256 + tid;
  int myy = ys[i];
  atomicAdd(&cnt[myy], 1);
  int fp = -1;
  for (int j = 0; j < NR; ++j) {
    if (j != i && ys[j] == myy) { fp = j; break; }
  }
  fpos[i] = fp;
}

// ---------------- kernel 3: slot0 (fp32 dot with first positive) ------------
__global__ __launch_bounds__(256) void k_slot0(const float* __restrict__ x,
                                               const float* __restrict__ norms,
                                               const int* __restrict__ fpos,
                                               float* __restrict__ slot0) {
  int row = blockIdx.x * 4 + (threadIdx.x >> 6);
  int lane = threadIdx.x & 63;
  int j = fpos[row];
  float s0 = 0.f;
  if (j >= 0) {
    const float4* a = reinterpret_cast<const float4*>(x + (size_t)row * DIM);
    const float4* b = reinterpret_cast<const float4*>(x + (size_t)j * DIM);
    float d = 0.f;
#pragma unroll
    for (int it = 0; it < 4; ++it) {
      float4 va = a[it * 64 + lane], vb = b[it * 64 + lane];
      d += va.x * vb.x + va.y * vb.y + va.z * vb.z + va.w * vb.w;
    }
#pragma unroll
    for (int dd = 1; dd < 64; dd <<= 1) d += __shfl_xor(d, dd);
    s0 = (d / (norms[row] * norms[j]) + 1.0f) * 0.25f;
  }
  if (lane == 0) slot0[row] = s0;
}

// ---------------- kernel 4: CE per row --------------------------------------
__global__ __launch_bounds__(256) void k_ce(const float* __restrict__ yp,
                                            const int* __restrict__ y,
                                            float* __restrict__ ce) {
  int row = blockIdx.x * 4 + (threadIdx.x >> 6);
  int lane = threadIdx.x & 63;
  const float4* p = reinterpret_cast<const float4*>(yp + (size_t)row * NCLS);
  float4 v0 = p[lane], v1 = p[lane + 64];
  float m = fmaxf(fmaxf(fmaxf(v0.x, v0.y), fmaxf(v0.z, v0.w)),
                  fmaxf(fmaxf(v1.x, v1.y), fmaxf(v1.z, v1.w)));
#pragma unroll
  for (int d = 1; d < 64; d <<= 1) m = fmaxf(m, __shfl_xor(m, d));
  float s = __expf(v0.x - m) + __expf(v0.y - m) + __expf(v0.z - m) + __expf(v0.w - m) +
            __expf(v1.x - m) + __expf(v1.y - m) + __expf(v1.z - m) + __expf(v1.w - m);
#pragma unroll
  for (int d = 1; d < 64; d <<= 1) s += __shfl_xor(s, d);
  if (lane == 0) {
    float py = yp[(size_t)row * NCLS + y[row]];
    ce[row] = logf(s) + m - py;
  }
}

// ---------------- kernel 5: bf16 MFMA GEMM + masked exp row-sums ------------
// sim = (xn . xn^T + 1) * 0.25 ; accumulate exp(sim) over j with y_j != y_i
// per 128x128 tile; partial row sums -> part[col_block][row]
__global__ __launch_bounds__(256) void k_gemm(const unsigned short* __restrict__ xn,
                                              const int* __restrict__ y,
                                              float* __restrict__ part) {
  __shared__ unsigned short As[128][64];
  __shared__ unsigned short Bs[128][64];
  __shared__ int yrow[128], ycol[128];
  __shared__ float rowsum[128][2];

  const int tid = threadIdx.x;
  const int w = tid >> 6, lane = tid & 63;
  const int rb = blockIdx.y, cb = blockIdx.x;
  const int rowbase = rb * 128, colbase = cb * 128;

  if (tid < 128) yrow[tid] = y[rowbase + tid];
  else ycol[tid - 128] = y[colbase + tid - 128];

  f32x4 acc[4][4] = {};
  const int wr = (w >> 1) * 64, wc = (w & 1) * 64;
  const int r0 = lane & 15;
  const int kgrp = (lane >> 4) * 8;

  for (int kt = 0; kt < 16; ++kt) {
    // stage A,B tiles: 16KB each, 4 rounds of (4 waves x 1KB) via global_load_lds
#pragma unroll
    for (int q = 0; q < 4; ++q) {
      int o = (q << 12) + (w << 10) + (lane << 4);  // byte offset in tile
      int row = o >> 7;                             // 128 B per row
      int colb = o & 127;
      const unsigned short* ga = xn + (size_t)(rowbase + row) * DIM + kt * 64 + (colb >> 1);
      const unsigned short* gb = xn + (size_t)(colbase + row) * DIM + kt * 64 + (colb >> 1);
      __builtin_amdgcn_global_load_lds(
          (const __attribute__((address_space(1))) void*)ga,
          (__attribute__((address_space(3))) void*)((char*)&As[0][0] + (q << 12) + (w << 10)),
          16, 0, 0);
      __builtin_amdgcn_global_load_lds(
          (const __attribute__((address_space(1))) void*)gb,
          (__attribute__((address_space(3))) void*)((char*)&Bs[0][0] + (q << 12) + (w << 10)),
          16, 0, 0);
    }
    __syncthreads();
#pragma unroll
    for (int kk = 0; kk < 2; ++kk) {
      bf16x8 a[4], b[4];
      int kq = kgrp + kk * 32;
#pragma unroll
      for (int m = 0; m < 4; ++m) a[m] = *(const bf16x8*)&As[wr + m * 16 + r0][kq];
#pragma unroll
      for (int n = 0; n < 4; ++n) b[n] = *(const bf16x8*)&Bs[wc + n * 16 + r0][kq];
#pragma unroll
      for (int m = 0; m < 4; ++m)
#pragma unroll
        for (int n = 0; n < 4; ++n)
          acc[m][n] = __builtin_amdgcn_mfma_f32_16x16x32_bf16(a[m], b[n], acc[m][n], 0, 0, 0);
    }
    __syncthreads();
  }

  // epilogue: masked exp + row reduce
  const int g = lane >> 4;  // 0..3
#pragma unroll
  for (int m = 0; m < 4; ++m) {
    float rs[4] = {0.f, 0.f, 0.f, 0.f};
    int yr[4];
#pragma unroll
    for (int reg = 0; reg < 4; ++reg) yr[reg] = yrow[wr + m * 16 + g * 4 + reg];
#pragma unroll
    for (int n = 0; n < 4; ++n) {
      int yc = ycol[wc + n * 16 + r0];
#pragma unroll
      for (int reg = 0; reg < 4; ++reg) {
        float v = acc[m][n][reg];
        rs[reg] += (yr[reg] == yc) ? 0.f : __expf((v + 1.0f) * 0.25f);
      }
    }
#pragma unroll
    for (int d = 1; d < 16; d <<= 1)
#pragma unroll
      for (int reg = 0; reg < 4; ++reg) rs[reg] += __shfl_xor(rs[reg], d);
    if (r0 == 0) {
#pragma unroll
      for (int reg = 0; reg < 4; ++reg)
        rowsum[wr + m * 16 + g * 4 + reg][w & 1] = rs[reg];
    }
  }
  __syncthreads();
  if (tid < 128)
    part[(size_t)cb * NR + rowbase + tid] = rowsum[tid][0] + rowsum[tid][1];
}

// ---------------- kernel 6: final reduction ---------------------------------
__global__ __launch_bounds__(256) void k_final(const float* __restrict__ part,
                                               const float* __restrict__ slot0,
                                               const int* __restrict__ cnt,
                                               const int* __restrict__ y,
                                               const float* __restrict__ ce,
                                               float* __restrict__ out) {
  __shared__ float red[256];
  int tid = threadIdx.x;
  float acc = 0.f;
  for (int i = tid; i < NR; i += 256) {
    float S = 0.f;
#pragma unroll
    for (int c = 0; c < 32; ++c) S += part[(size_t)c * NR + i];
    float s0 = slot0[i];
    float zeros = 4094.0f + (float)cnt[y[i]];  // 8190 - (4096 - cnt)
    float cl = logf(__expf(s0) + S + zeros) - s0;
    acc += 0.5f * (cl + ce[i]);
  }
  red[tid] = acc;
  __syncthreads();
  for (int s = 128; s > 0; s >>= 1) {
    if (tid < s) red[tid] += red[tid + s];
    __syncthreads();
  }
  if (tid == 0) out[0] = red[0] / (float)NR;
}

extern "C" void kernel_launch(void* const* d_in, const int* in_sizes, int n_in,
                              void* d_out, int out_size, void* d_ws, size_t ws_size,
                              hipStream_t stream) {
  const float* x = (const float*)d_in[0];
  const int* y = (const int*)d_in[1];
  const float* yp = (const float*)d_in[2];
  float* out = (float*)d_out;

  char* w = (char*)d_ws;
  unsigned short* xn = (unsigned short*)w;        // 4096*1024*2 = 8388608 B
  float* norms = (float*)(w + 8388608);           // 16384 B
  int* cnt = (int*)(w + 8404992);                 // 2048 B
  int* fpos = (int*)(w + 8407040);                // 16384 B
  float* slot0 = (float*)(w + 8423424);           // 16384 B
  float* part = (float*)(w + 8439808);            // 32*4096*4 = 524288 B
  float* ce = (float*)(w + 8964096);              // 16384 B

  hipMemsetAsync(cnt, 0, NCLS * sizeof(int), stream);
  k_norm<<<1024, 256, 0, stream>>>(x, xn, norms);
  k_labels<<<16, 256, 0, stream>>>(y, cnt, fpos);
  k_slot0<<<1024, 256, 0, stream>>>(x, norms, fpos, slot0);
  k_ce<<<1024, 256, 0, stream>>>(yp, y, ce);
  dim3 g(32, 32);
  k_gemm<<<g, 256, 0, stream>>>(xn, y, part);
  k_final<<<1, 256, 0, stream>>>(part, slot0, cnt, y, ce, out);
}

// Round 2
// 102.158 us; speedup vs baseline: 4.6444x; 4.6444x over previous
//
#include <hip/hip_runtime.h>
#include <hip/hip_bf16.h>

#define NR 4096
#define DIM 1024
#define NCLS 512

typedef __attribute__((ext_vector_type(4))) float f32x4;
typedef __attribute__((ext_vector_type(8))) short bf16x8;

static __device__ __forceinline__ unsigned short f2bf(float f) {
  __hip_bfloat16 h = __float2bfloat16(f);
  return *reinterpret_cast<unsigned short*>(&h);
}

// ---------------- kernel 1: row norms + bf16 normalized copy ----------------
__global__ __launch_bounds__(256) void k_norm(const float* __restrict__ x,
                                              unsigned short* __restrict__ xn,
                                              float* __restrict__ norms) {
  int row = blockIdx.x * 4 + (threadIdx.x >> 6);
  int lane = threadIdx.x & 63;
  const float4* xr = reinterpret_cast<const float4*>(x + (size_t)row * DIM);
  float4 v[4];
  float s = 0.f;
#pragma unroll
  for (int it = 0; it < 4; ++it) {
    v[it] = xr[it * 64 + lane];
    s += v[it].x * v[it].x + v[it].y * v[it].y + v[it].z * v[it].z + v[it].w * v[it].w;
  }
#pragma unroll
  for (int d = 1; d < 64; d <<= 1) s += __shfl_xor(s, d);
  float nrm = fmaxf(sqrtf(s), 1e-8f);
  float inv = 1.0f / nrm;
  if (lane == 0) norms[row] = nrm;
  ushort4* xo = reinterpret_cast<ushort4*>(xn + (size_t)row * DIM);
#pragma unroll
  for (int it = 0; it < 4; ++it) {
    ushort4 u;
    u.x = f2bf(v[it].x * inv);
    u.y = f2bf(v[it].y * inv);
    u.z = f2bf(v[it].z * inv);
    u.w = f2bf(v[it].w * inv);
    xo[it * 64 + lane] = u;
  }
}

// ---------------- kernel 2a/2b: per-class count + first/second min index ----
__global__ __launch_bounds__(256) void k_label1(const int* __restrict__ y,
                                                int* __restrict__ cnt,
                                                int* __restrict__ min1) {
  int i = blockIdx.x * 256 + threadIdx.x;
  int c = y[i];
  atomicAdd(&cnt[c], 1);
  atomicMin(&min1[c], i);
}

__global__ __launch_bounds__(256) void k_label2(const int* __restrict__ y,
                                                const int* __restrict__ min1,
                                                int* __restrict__ min2) {
  int i = blockIdx.x * 256 + threadIdx.x;
  int c = y[i];
  if (min1[c] != i) atomicMin(&min2[c], i);
}

// ---------------- kernel 3: slot0 (fp32 dot with first positive) ------------
__global__ __launch_bounds__(256) void k_slot0(const float* __restrict__ x,
                                               const float* __restrict__ norms,
                                               const int* __restrict__ y,
                                               const int* __restrict__ min1,
                                               const int* __restrict__ min2,
                                               float* __restrict__ slot0) {
  int row = blockIdx.x * 4 + (threadIdx.x >> 6);
  int lane = threadIdx.x & 63;
  int c = y[row];
  int m1 = min1[c], m2 = min2[c];
  int j = (m1 == row) ? ((m2 >= NR) ? -1 : m2) : m1;
  float s0 = 0.f;
  if (j >= 0) {
    const float4* a = reinterpret_cast<const float4*>(x + (size_t)row * DIM);
    const float4* b = reinterpret_cast<const float4*>(x + (size_t)j * DIM);
    float d = 0.f;
#pragma unroll
    for (int it = 0; it < 4; ++it) {
      float4 va = a[it * 64 + lane], vb = b[it * 64 + lane];
      d += va.x * vb.x + va.y * vb.y + va.z * vb.z + va.w * vb.w;
    }
#pragma unroll
    for (int dd = 1; dd < 64; dd <<= 1) d += __shfl_xor(d, dd);
    s0 = (d / (norms[row] * norms[j]) + 1.0f) * 0.25f;
  }
  if (lane == 0) slot0[row] = s0;
}

// ---------------- kernel 4: CE per row --------------------------------------
__global__ __launch_bounds__(256) void k_ce(const float* __restrict__ yp,
                                            const int* __restrict__ y,
                                            float* __restrict__ ce) {
  int row = blockIdx.x * 4 + (threadIdx.x >> 6);
  int lane = threadIdx.x & 63;
  const float4* p = reinterpret_cast<const float4*>(yp + (size_t)row * NCLS);
  float4 v0 = p[lane], v1 = p[lane + 64];
  float m = fmaxf(fmaxf(fmaxf(v0.x, v0.y), fmaxf(v0.z, v0.w)),
                  fmaxf(fmaxf(v1.x, v1.y), fmaxf(v1.z, v1.w)));
#pragma unroll
  for (int d = 1; d < 64; d <<= 1) m = fmaxf(m, __shfl_xor(m, d));
  float s = __expf(v0.x - m) + __expf(v0.y - m) + __expf(v0.z - m) + __expf(v0.w - m) +
            __expf(v1.x - m) + __expf(v1.y - m) + __expf(v1.z - m) + __expf(v1.w - m);
#pragma unroll
  for (int d = 1; d < 64; d <<= 1) s += __shfl_xor(s, d);
  if (lane == 0) {
    float py = yp[(size_t)row * NCLS + y[row]];
    ce[row] = logf(s) + m - py;
  }
}

// ---------------- kernel 5: bf16 MFMA GEMM + masked exp row-sums ------------
// sim = (xn . xn^T + 1) * 0.25 ; accumulate exp(sim) over j with y_j != y_i
// per 128x128 tile; partial row sums -> part[col_block][row]
__global__ __launch_bounds__(256) void k_gemm(const unsigned short* __restrict__ xn,
                                              const int* __restrict__ y,
                                              float* __restrict__ part) {
  __shared__ unsigned short As[128][64];
  __shared__ unsigned short Bs[128][64];
  __shared__ int yrow[128], ycol[128];
  __shared__ float rowsum[128][2];

  const int tid = threadIdx.x;
  const int w = tid >> 6, lane = tid & 63;
  const int rb = blockIdx.y, cb = blockIdx.x;
  const int rowbase = rb * 128, colbase = cb * 128;

  if (tid < 128) yrow[tid] = y[rowbase + tid];
  else ycol[tid - 128] = y[colbase + tid - 128];

  f32x4 acc[4][4] = {};
  const int wr = (w >> 1) * 64, wc = (w & 1) * 64;
  const int r0 = lane & 15;
  const int kgrp = (lane >> 4) * 8;

  for (int kt = 0; kt < 16; ++kt) {
    // stage A,B tiles: 16KB each, 4 rounds of (4 waves x 1KB) via global_load_lds
#pragma unroll
    for (int q = 0; q < 4; ++q) {
      int o = (q << 12) + (w << 10) + (lane << 4);  // byte offset in tile
      int row = o >> 7;                             // 128 B per row
      int colb = o & 127;
      const unsigned short* ga = xn + (size_t)(rowbase + row) * DIM + kt * 64 + (colb >> 1);
      const unsigned short* gb = xn + (size_t)(colbase + row) * DIM + kt * 64 + (colb >> 1);
      __builtin_amdgcn_global_load_lds(
          (const __attribute__((address_space(1))) void*)ga,
          (__attribute__((address_space(3))) void*)((char*)&As[0][0] + (q << 12) + (w << 10)),
          16, 0, 0);
      __builtin_amdgcn_global_load_lds(
          (const __attribute__((address_space(1))) void*)gb,
          (__attribute__((address_space(3))) void*)((char*)&Bs[0][0] + (q << 12) + (w << 10)),
          16, 0, 0);
    }
    __syncthreads();
#pragma unroll
    for (int kk = 0; kk < 2; ++kk) {
      bf16x8 a[4], b[4];
      int kq = kgrp + kk * 32;
#pragma unroll
      for (int m = 0; m < 4; ++m) a[m] = *(const bf16x8*)&As[wr + m * 16 + r0][kq];
#pragma unroll
      for (int n = 0; n < 4; ++n) b[n] = *(const bf16x8*)&Bs[wc + n * 16 + r0][kq];
#pragma unroll
      for (int m = 0; m < 4; ++m)
#pragma unroll
        for (int n = 0; n < 4; ++n)
          acc[m][n] = __builtin_amdgcn_mfma_f32_16x16x32_bf16(a[m], b[n], acc[m][n], 0, 0, 0);
    }
    __syncthreads();
  }

  // epilogue: masked exp + row reduce
  const int g = lane >> 4;  // 0..3
#pragma unroll
  for (int m = 0; m < 4; ++m) {
    float rs[4] = {0.f, 0.f, 0.f, 0.f};
    int yr[4];
#pragma unroll
    for (int reg = 0; reg < 4; ++reg) yr[reg] = yrow[wr + m * 16 + g * 4 + reg];
#pragma unroll
    for (int n = 0; n < 4; ++n) {
      int yc = ycol[wc + n * 16 + r0];
#pragma unroll
      for (int reg = 0; reg < 4; ++reg) {
        float v = acc[m][n][reg];
        rs[reg] += (yr[reg] == yc) ? 0.f : __expf((v + 1.0f) * 0.25f);
      }
    }
#pragma unroll
    for (int d = 1; d < 16; d <<= 1)
#pragma unroll
      for (int reg = 0; reg < 4; ++reg) rs[reg] += __shfl_xor(rs[reg], d);
    if (r0 == 0) {
#pragma unroll
      for (int reg = 0; reg < 4; ++reg)
        rowsum[wr + m * 16 + g * 4 + reg][w & 1] = rs[reg];
    }
  }
  __syncthreads();
  if (tid < 128)
    part[(size_t)cb * NR + rowbase + tid] = rowsum[tid][0] + rowsum[tid][1];
}

// ---------------- kernel 6: final reduction ---------------------------------
__global__ __launch_bounds__(256) void k_final(const float* __restrict__ part,
                                               const float* __restrict__ slot0,
                                               const int* __restrict__ cnt,
                                               const int* __restrict__ y,
                                               const float* __restrict__ ce,
                                               float* __restrict__ out) {
  __shared__ float red[256];
  int tid = threadIdx.x;
  float acc = 0.f;
  for (int i = tid; i < NR; i += 256) {
    float S = 0.f;
#pragma unroll
    for (int c = 0; c < 32; ++c) S += part[(size_t)c * NR + i];
    float s0 = slot0[i];
    float zeros = 4094.0f + (float)cnt[y[i]];  // 8191 - 1 - (4096 - cnt)
    float cl = logf(__expf(s0) + S + zeros) - s0;
    acc += 0.5f * (cl + ce[i]);
  }
  red[tid] = acc;
  __syncthreads();
  for (int s = 128; s > 0; s >>= 1) {
    if (tid < s) red[tid] += red[tid + s];
    __syncthreads();
  }
  if (tid == 0) out[0] = red[0] / (float)NR;
}

extern "C" void kernel_launch(void* const* d_in, const int* in_sizes, int n_in,
                              void* d_out, int out_size, void* d_ws, size_t ws_size,
                              hipStream_t stream) {
  const float* x = (const float*)d_in[0];
  const int* y = (const int*)d_in[1];
  const float* yp = (const float*)d_in[2];
  float* out = (float*)d_out;

  char* w = (char*)d_ws;
  unsigned short* xn = (unsigned short*)w;        // 4096*1024*2 = 8388608 B
  float* norms = (float*)(w + 8388608);           // 16384 B
  int* cnt = (int*)(w + 8404992);                 // 2048 B
  int* min1 = (int*)(w + 8407040);                // 2048 B
  int* min2 = (int*)(w + 8409088);                // 2048 B
  float* slot0 = (float*)(w + 8411136);           // 16384 B
  float* part = (float*)(w + 8427520);            // 32*4096*4 = 524288 B
  float* ce = (float*)(w + 8951808);              // 16384 B

  hipMemsetAsync(cnt, 0, NCLS * sizeof(int), stream);
  hipMemsetAsync(min1, 0x7f, NCLS * sizeof(int), stream);  // ~2.1e9 > NR
  hipMemsetAsync(min2, 0x7f, NCLS * sizeof(int), stream);
  k_norm<<<1024, 256, 0, stream>>>(x, xn, norms);
  k_label1<<<16, 256, 0, stream>>>(y, cnt, min1);
  k_label2<<<16, 256, 0, stream>>>(y, min1, min2);
  k_slot0<<<1024, 256, 0, stream>>>(x, norms, y, min1, min2, slot0);
  k_ce<<<1024, 256, 0, stream>>>(yp, y, ce);
  dim3 g(32, 32);
  k_gemm<<<g, 256, 0, stream>>>(xn, y, part);
  k_final<<<1, 256, 0, stream>>>(part, slot0, cnt, y, ce, out);
}

// Round 3
// 74.865 us; speedup vs baseline: 6.3375x; 1.3646x over previous
//
#include <hip/hip_runtime.h>
#include <hip/hip_bf16.h>

#define NR 4096
#define DIM 1024
#define NCLS 512

typedef __attribute__((ext_vector_type(4))) float f32x4;
typedef __attribute__((ext_vector_type(8))) short bf16x8;

static __device__ __forceinline__ unsigned short f2bf(float f) {
  __hip_bfloat16 h = __float2bfloat16(f);
  return *reinterpret_cast<unsigned short*>(&h);
}

// ---- kernel 1: fused prep -------------------------------------------------
// blocks 0..1023   : row norms -> bf16 normalized copy (4 rows/block)
// blocks 1024..2047: CE per row (4 rows/block)
// block 2048       : label stats (cnt, fpos via min1/min2), zero slot0, zero out
__global__ __launch_bounds__(256) void k_prep(const float* __restrict__ x,
                                              const int* __restrict__ y,
                                              const float* __restrict__ yp,
                                              unsigned short* __restrict__ xn,
                                              int* __restrict__ cnt,
                                              int* __restrict__ fpos,
                                              float* __restrict__ slot0,
                                              float* __restrict__ ce,
                                              float* __restrict__ out) {
  const int b = blockIdx.x;
  const int tid = threadIdx.x;
  if (b < 1024) {
    // ---- normalize path ----
    int row = b * 4 + (tid >> 6);
    int lane = tid & 63;
    const float4* xr = reinterpret_cast<const float4*>(x + (size_t)row * DIM);
    float4 v[4];
    float s = 0.f;
#pragma unroll
    for (int it = 0; it < 4; ++it) {
      v[it] = xr[it * 64 + lane];
      s += v[it].x * v[it].x + v[it].y * v[it].y + v[it].z * v[it].z + v[it].w * v[it].w;
    }
#pragma unroll
    for (int d = 1; d < 64; d <<= 1) s += __shfl_xor(s, d);
    float inv = 1.0f / fmaxf(sqrtf(s), 1e-8f);
    ushort4* xo = reinterpret_cast<ushort4*>(xn + (size_t)row * DIM);
#pragma unroll
    for (int it = 0; it < 4; ++it) {
      ushort4 u;
      u.x = f2bf(v[it].x * inv);
      u.y = f2bf(v[it].y * inv);
      u.z = f2bf(v[it].z * inv);
      u.w = f2bf(v[it].w * inv);
      xo[it * 64 + lane] = u;
    }
  } else if (b < 2048) {
    // ---- CE path ----
    int row = (b - 1024) * 4 + (tid >> 6);
    int lane = tid & 63;
    const float4* p = reinterpret_cast<const float4*>(yp + (size_t)row * NCLS);
    float4 v0 = p[lane], v1 = p[lane + 64];
    float m = fmaxf(fmaxf(fmaxf(v0.x, v0.y), fmaxf(v0.z, v0.w)),
                    fmaxf(fmaxf(v1.x, v1.y), fmaxf(v1.z, v1.w)));
#pragma unroll
    for (int d = 1; d < 64; d <<= 1) m = fmaxf(m, __shfl_xor(m, d));
    float s = __expf(v0.x - m) + __expf(v0.y - m) + __expf(v0.z - m) + __expf(v0.w - m) +
              __expf(v1.x - m) + __expf(v1.y - m) + __expf(v1.z - m) + __expf(v1.w - m);
#pragma unroll
    for (int d = 1; d < 64; d <<= 1) s += __shfl_xor(s, d);
    if (lane == 0) {
      float py = yp[(size_t)row * NCLS + y[row]];
      ce[row] = logf(s) + m - py;
    }
  } else {
    // ---- label stats path (single block) ----
    __shared__ int ys[NR];
    __shared__ int scnt[NCLS], sm1[NCLS], sm2[NCLS];
    for (int j = tid; j < NR; j += 256) ys[j] = y[j];
    for (int c = tid; c < NCLS; c += 256) { scnt[c] = 0; sm1[c] = NR; sm2[c] = NR; }
    __syncthreads();
    for (int i = tid; i < NR; i += 256) {
      int c = ys[i];
      atomicAdd(&scnt[c], 1);
      atomicMin(&sm1[c], i);
    }
    __syncthreads();
    for (int i = tid; i < NR; i += 256) {
      int c = ys[i];
      if (sm1[c] != i) atomicMin(&sm2[c], i);
    }
    __syncthreads();
    for (int i = tid; i < NR; i += 256) {
      int c = ys[i];
      int m1 = sm1[c];
      int j = (m1 == i) ? ((sm2[c] >= NR) ? -1 : sm2[c]) : m1;
      fpos[i] = j;
      slot0[i] = 0.f;
    }
    for (int c = tid; c < NCLS; c += 256) cnt[c] = scnt[c];
    if (tid == 0) out[0] = 0.f;
  }
}

// ---- kernel 2: symmetric bf16 MFMA GEMM + masked exp row/col sums ----------
// Only tiles with cb >= rb (528 of 1024). Tile (rb,cb):
//   row-sums of masked exp  -> part[cb][rowbase + r]
//   col-sums (rb != cb)     -> part[rb][colbase + c]   (sim & mask symmetric)
// slot0 scatter: element (i, fpos[i]) of sim is written when encountered.
__global__ __launch_bounds__(256) void k_gemm(const unsigned short* __restrict__ xn,
                                              const int* __restrict__ y,
                                              const int* __restrict__ fpos,
                                              float* __restrict__ part,
                                              float* __restrict__ slot0) {
  __shared__ unsigned short As[128][64];
  __shared__ unsigned short Bs[128][64];
  __shared__ int yrow[128], ycol[128], frow[128], fcol[128];
  __shared__ float rowsum[128][2], colsum[128][2];

  const int tid = threadIdx.x;
  const int w = tid >> 6, lane = tid & 63;

  // decode triangular tile index
  int t = blockIdx.x, rb = 0;
  while (t >= 32 - rb) { t -= 32 - rb; ++rb; }
  const int cb = rb + t;
  const int rowbase = rb * 128, colbase = cb * 128;

  if (tid < 128) { yrow[tid] = y[rowbase + tid]; frow[tid] = fpos[rowbase + tid]; }
  else { ycol[tid - 128] = y[colbase + tid - 128]; fcol[tid - 128] = fpos[colbase + tid - 128]; }

  f32x4 acc[4][4] = {};
  const int wr = (w >> 1) * 64, wc = (w & 1) * 64;
  const int r0 = lane & 15;
  const int kgrp = (lane >> 4) * 8;

  for (int kt = 0; kt < 16; ++kt) {
#pragma unroll
    for (int q = 0; q < 4; ++q) {
      int o = (q << 12) + (w << 10) + (lane << 4);  // byte offset in tile
      int row = o >> 7;                             // 128 B per row
      int colb = o & 127;
      const unsigned short* ga = xn + (size_t)(rowbase + row) * DIM + kt * 64 + (colb >> 1);
      const unsigned short* gb = xn + (size_t)(colbase + row) * DIM + kt * 64 + (colb >> 1);
      __builtin_amdgcn_global_load_lds(
          (const __attribute__((address_space(1))) void*)ga,
          (__attribute__((address_space(3))) void*)((char*)&As[0][0] + (q << 12) + (w << 10)),
          16, 0, 0);
      __builtin_amdgcn_global_load_lds(
          (const __attribute__((address_space(1))) void*)gb,
          (__attribute__((address_space(3))) void*)((char*)&Bs[0][0] + (q << 12) + (w << 10)),
          16, 0, 0);
    }
    __syncthreads();
#pragma unroll
    for (int kk = 0; kk < 2; ++kk) {
      bf16x8 a[4], b[4];
      int kq = kgrp + kk * 32;
#pragma unroll
      for (int m = 0; m < 4; ++m) a[m] = *(const bf16x8*)&As[wr + m * 16 + r0][kq];
#pragma unroll
      for (int n = 0; n < 4; ++n) b[n] = *(const bf16x8*)&Bs[wc + n * 16 + r0][kq];
#pragma unroll
      for (int m = 0; m < 4; ++m)
#pragma unroll
        for (int n = 0; n < 4; ++n)
          acc[m][n] = __builtin_amdgcn_mfma_f32_16x16x32_bf16(a[m], b[n], acc[m][n], 0, 0, 0);
    }
    __syncthreads();
  }

  // epilogue: masked exp, row sums + col sums, slot0 scatter
  const int g = lane >> 4;  // 0..3
  float csn[4] = {0.f, 0.f, 0.f, 0.f};
#pragma unroll
  for (int m = 0; m < 4; ++m) {
    float rs[4] = {0.f, 0.f, 0.f, 0.f};
    int yr[4], fr[4], Rl[4];
#pragma unroll
    for (int reg = 0; reg < 4; ++reg) {
      Rl[reg] = wr + m * 16 + g * 4 + reg;
      yr[reg] = yrow[Rl[reg]];
      fr[reg] = frow[Rl[reg]];
    }
#pragma unroll
    for (int n = 0; n < 4; ++n) {
      int Cl = wc + n * 16 + r0;
      int yc = ycol[Cl];
      int fc = fcol[Cl];
      int gc = colbase + Cl;
#pragma unroll
      for (int reg = 0; reg < 4; ++reg) {
        float sv = (acc[m][n][reg] + 1.0f) * 0.25f;
        float e = (yr[reg] == yc) ? 0.f : __expf(sv);
        rs[reg] += e;
        csn[n] += e;
        int gr = rowbase + Rl[reg];
        if (fr[reg] == gc) slot0[gr] = sv;
        if (rb != cb && fc == gr) slot0[gc] = sv;
      }
    }
#pragma unroll
    for (int d = 1; d < 16; d <<= 1)
#pragma unroll
      for (int reg = 0; reg < 4; ++reg) rs[reg] += __shfl_xor(rs[reg], d);
    if (r0 == 0) {
#pragma unroll
      for (int reg = 0; reg < 4; ++reg)
        rowsum[wr + m * 16 + g * 4 + reg][w & 1] = rs[reg];
    }
  }
  // col-sum reduce across row groups (lanes r0, r0+16, r0+32, r0+48)
#pragma unroll
  for (int n = 0; n < 4; ++n) {
    csn[n] += __shfl_xor(csn[n], 16);
    csn[n] += __shfl_xor(csn[n], 32);
  }
  if (g == 0) {
#pragma unroll
    for (int n = 0; n < 4; ++n) colsum[wc + n * 16 + r0][w >> 1] = csn[n];
  }
  __syncthreads();
  if (tid < 128) {
    part[(size_t)cb * NR + rowbase + tid] = rowsum[tid][0] + rowsum[tid][1];
    if (rb != cb)
      part[(size_t)rb * NR + colbase + tid] = colsum[tid][0] + colsum[tid][1];
  }
}

// ---- kernel 3: final loss reduction ----------------------------------------
__global__ __launch_bounds__(256) void k_final(const float* __restrict__ part,
                                               const float* __restrict__ slot0,
                                               const int* __restrict__ cnt,
                                               const int* __restrict__ y,
                                               const float* __restrict__ ce,
                                               float* __restrict__ out) {
  __shared__ float red[256];
  const int tid = threadIdx.x;
  const int r = blockIdx.x * 256 + tid;
  float S = 0.f;
#pragma unroll
  for (int b = 0; b < 32; ++b) S += part[(size_t)b * NR + r];
  float s0 = slot0[r];
  float zeros = 4094.0f + (float)cnt[y[r]];  // 8190 - (4096 - cnt)
  float cl = logf(__expf(s0) + S + zeros) - s0;
  red[tid] = 0.5f * (cl + ce[r]);
  __syncthreads();
  for (int s = 128; s > 0; s >>= 1) {
    if (tid < s) red[tid] += red[tid + s];
    __syncthreads();
  }
  if (tid == 0) atomicAdd(out, red[0] / (float)NR);
}

extern "C" void kernel_launch(void* const* d_in, const int* in_sizes, int n_in,
                              void* d_out, int out_size, void* d_ws, size_t ws_size,
                              hipStream_t stream) {
  const float* x = (const float*)d_in[0];
  const int* y = (const int*)d_in[1];
  const float* yp = (const float*)d_in[2];
  float* out = (float*)d_out;

  char* w = (char*)d_ws;
  unsigned short* xn = (unsigned short*)w;   // 8388608 B
  int* cnt = (int*)(w + 8388608);            // 2048 B
  int* fpos = (int*)(w + 8390656);           // 16384 B
  float* slot0 = (float*)(w + 8407040);      // 16384 B
  float* part = (float*)(w + 8423424);       // 32*4096*4 = 524288 B
  float* ce = (float*)(w + 8947712);         // 16384 B

  k_prep<<<2049, 256, 0, stream>>>(x, y, yp, xn, cnt, fpos, slot0, ce, out);
  k_gemm<<<528, 256, 0, stream>>>(xn, y, fpos, part, slot0);
  k_final<<<16, 256, 0, stream>>>(part, slot0, cnt, y, ce, out);
}

// Round 4
// 55.369 us; speedup vs baseline: 8.5690x; 1.3521x over previous
//
#include <hip/hip_runtime.h>
#include <hip/hip_bf16.h>

#define NR 4096
#define DIM 1024
#define NCLS 512

typedef __attribute__((ext_vector_type(4))) float f32x4;
typedef __attribute__((ext_vector_type(8))) short bf16x8;

static __device__ __forceinline__ unsigned short f2bf(float f) {
  __hip_bfloat16 h = __float2bfloat16(f);
  return *reinterpret_cast<unsigned short*>(&h);
}

// ---- kernel 1: fused prep -------------------------------------------------
// blocks 0..1023   : row norms -> bf16 normalized copy (4 rows/block)
// blocks 1024..2047: CE per row (4 rows/block)
// block 2048       : label stats (cnt, fpos via min1/min2), zero slot0, zero out
__global__ __launch_bounds__(256) void k_prep(const float* __restrict__ x,
                                              const int* __restrict__ y,
                                              const float* __restrict__ yp,
                                              unsigned short* __restrict__ xn,
                                              int* __restrict__ cnt,
                                              int* __restrict__ fpos,
                                              float* __restrict__ slot0,
                                              float* __restrict__ ce,
                                              float* __restrict__ out) {
  const int b = blockIdx.x;
  const int tid = threadIdx.x;
  if (b < 1024) {
    int row = b * 4 + (tid >> 6);
    int lane = tid & 63;
    const float4* xr = reinterpret_cast<const float4*>(x + (size_t)row * DIM);
    float4 v[4];
    float s = 0.f;
#pragma unroll
    for (int it = 0; it < 4; ++it) {
      v[it] = xr[it * 64 + lane];
      s += v[it].x * v[it].x + v[it].y * v[it].y + v[it].z * v[it].z + v[it].w * v[it].w;
    }
#pragma unroll
    for (int d = 1; d < 64; d <<= 1) s += __shfl_xor(s, d);
    float inv = 1.0f / fmaxf(sqrtf(s), 1e-8f);
    ushort4* xo = reinterpret_cast<ushort4*>(xn + (size_t)row * DIM);
#pragma unroll
    for (int it = 0; it < 4; ++it) {
      ushort4 u;
      u.x = f2bf(v[it].x * inv);
      u.y = f2bf(v[it].y * inv);
      u.z = f2bf(v[it].z * inv);
      u.w = f2bf(v[it].w * inv);
      xo[it * 64 + lane] = u;
    }
  } else if (b < 2048) {
    int row = (b - 1024) * 4 + (tid >> 6);
    int lane = tid & 63;
    const float4* p = reinterpret_cast<const float4*>(yp + (size_t)row * NCLS);
    float4 v0 = p[lane], v1 = p[lane + 64];
    float m = fmaxf(fmaxf(fmaxf(v0.x, v0.y), fmaxf(v0.z, v0.w)),
                    fmaxf(fmaxf(v1.x, v1.y), fmaxf(v1.z, v1.w)));
#pragma unroll
    for (int d = 1; d < 64; d <<= 1) m = fmaxf(m, __shfl_xor(m, d));
    float s = __expf(v0.x - m) + __expf(v0.y - m) + __expf(v0.z - m) + __expf(v0.w - m) +
              __expf(v1.x - m) + __expf(v1.y - m) + __expf(v1.z - m) + __expf(v1.w - m);
#pragma unroll
    for (int d = 1; d < 64; d <<= 1) s += __shfl_xor(s, d);
    if (lane == 0) {
      float py = yp[(size_t)row * NCLS + y[row]];
      ce[row] = logf(s) + m - py;
    }
  } else {
    __shared__ int ys[NR];
    __shared__ int scnt[NCLS], sm1[NCLS], sm2[NCLS];
    for (int j = tid; j < NR; j += 256) ys[j] = y[j];
    for (int c = tid; c < NCLS; c += 256) { scnt[c] = 0; sm1[c] = NR; sm2[c] = NR; }
    __syncthreads();
    for (int i = tid; i < NR; i += 256) {
      int c = ys[i];
      atomicAdd(&scnt[c], 1);
      atomicMin(&sm1[c], i);
    }
    __syncthreads();
    for (int i = tid; i < NR; i += 256) {
      int c = ys[i];
      if (sm1[c] != i) atomicMin(&sm2[c], i);
    }
    __syncthreads();
    for (int i = tid; i < NR; i += 256) {
      int c = ys[i];
      int m1 = sm1[c];
      int j = (m1 == i) ? ((sm2[c] >= NR) ? -1 : sm2[c]) : m1;
      fpos[i] = j;
      slot0[i] = 0.f;
    }
    for (int c = tid; c < NCLS; c += 256) cnt[c] = scnt[c];
    if (tid == 0) out[0] = 0.f;
  }
}

// ---- kernel 2: 8-phase 256x256 bf16 MFMA GEMM + fused masked-exp epilogue --
// LDS: 2 bufs x {A0,A1,B0,B1} 16KB half-tiles (128 rows x 64 bf16), 128KB.
// st_16x32 swizzle: LDS dest linear; global SOURCE pre-inverse-swizzled;
// ds_read address swizzled. swz(b) = b ^ (((b>>9)&1)<<5)  (involution).
// Stage schedule (iter i, t0=2i, t1=2i+1): ph0:A0(t1) ph1:A1(t1)
// ph2:B0(t0+2) ph3:B1(t0+2)[vmcnt4] ph4:A0(t0+2) ph5:A1(t0+2)
// ph6:B0(t1+2) ph7:B1(t1+2)[vmcnt4]. Every staged slot's last read ended
// >=1 barrier before the stage issue; vmcnt(4) leaves exactly the 2 newest
// half-tiles in flight.

#define STAGE(SSLOT, GROWBASE, KT)                                               \
  _Pragma("unroll") for (int q = 0; q < 2; ++q) {                                \
    const char* _src = (const char*)xn +                                         \
        (size_t)((GROWBASE) + srow[q]) * 2048 + (size_t)(KT) * 128 + scolb[q];   \
    __builtin_amdgcn_global_load_lds(                                            \
        (const __attribute__((address_space(1))) void*)_src,                     \
        (__attribute__((address_space(3))) void*)(lds + (SSLOT) + q * 8192 +     \
                                                  (w << 10)),                    \
        16, 0, 0);                                                               \
  }

#define PHASE(BUFB, MF0, LOADB, SSLOT, SBASE, SKT, VM)                           \
  {                                                                              \
    _Pragma("unroll") for (int mm = 0; mm < 2; ++mm)                             \
      _Pragma("unroll") for (int kk = 0; kk < 2; ++kk)                           \
        afr[mm][kk] = *(const bf16x8*)(lds + (BUFB) + ABaseW +                   \
                                       ((MF0) + mm) * 2048 + kk * 64 + kswz);    \
    if (LOADB) {                                                                 \
      _Pragma("unroll") for (int nf = 0; nf < 4; ++nf)                           \
        _Pragma("unroll") for (int kk = 0; kk < 2; ++kk)                         \
          bfr[nf][kk] = *(const bf16x8*)(lds + (BUFB) + BBaseW +                 \
                                         nf * 2048 + kk * 64 + kswz);            \
    }                                                                            \
    STAGE(SSLOT, SBASE, SKT)                                                     \
    if (VM) asm volatile("s_waitcnt vmcnt(4)" ::: "memory");                     \
    __builtin_amdgcn_s_barrier();                                                \
    asm volatile("s_waitcnt lgkmcnt(0)" ::: "memory");                           \
    __builtin_amdgcn_sched_barrier(0);                                           \
    __builtin_amdgcn_s_setprio(1);                                               \
    _Pragma("unroll") for (int kk = 0; kk < 2; ++kk)                             \
      _Pragma("unroll") for (int mm = 0; mm < 2; ++mm)                           \
        _Pragma("unroll") for (int nf = 0; nf < 4; ++nf)                         \
          acc[(MF0) + mm][nf] = __builtin_amdgcn_mfma_f32_16x16x32_bf16(         \
              afr[mm][kk], bfr[nf][kk], acc[(MF0) + mm][nf], 0, 0, 0);           \
    __builtin_amdgcn_s_setprio(0);                                               \
    __builtin_amdgcn_sched_barrier(0);                                           \
    __builtin_amdgcn_s_barrier();                                                \
  }

__global__ __launch_bounds__(512, 2) void k_gemm(const unsigned short* __restrict__ xn,
                                                 const int* __restrict__ y,
                                                 const int* __restrict__ fpos,
                                                 float* __restrict__ part,
                                                 float* __restrict__ slot0) {
  __shared__ char lds[131072];
  const int tid = threadIdx.x;
  const int w = tid >> 6, lane = tid & 63;
  const int wr = w >> 2, wcn = w & 3;
  const int r0 = lane & 15, klo = lane >> 4;

  const int bid = blockIdx.x;
  const int swzb = (bid & 7) * 32 + (bid >> 3);  // XCD swizzle, 256%8==0 ok
  const int rb = swzb >> 4, cb = swzb & 15;
  const int rowbase = rb * 256, colbase = cb * 256;

  const int kswz = (klo * 16) ^ (((r0 >> 2) & 1) << 5);
  const int ABaseW = wr * 16384 + r0 * 128;
  const int BBaseW = 32768 + (wcn >> 1) * 16384 + (wcn & 1) * 8192 + r0 * 128;

  int srow[2], scolb[2];
#pragma unroll
  for (int q = 0; q < 2; ++q) {
    int D = q * 8192 + tid * 16;
    int L = D ^ (((D >> 9) & 1) << 5);
    srow[q] = L >> 7;
    scolb[q] = L & 127;
  }

  f32x4 acc[8][4] = {};

  // prologue: K-tile 0 -> buf0 fully; B halves of K-tile 1 -> buf1
  STAGE(0, rowbase, 0)
  STAGE(16384, rowbase + 128, 0)
  STAGE(32768, colbase, 0)
  STAGE(49152, colbase + 128, 0)
  STAGE(65536 + 32768, colbase, 1)
  STAGE(65536 + 49152, colbase + 128, 1)
  asm volatile("s_waitcnt vmcnt(4)" ::: "memory");
  __builtin_amdgcn_s_barrier();

  for (int i = 0; i < 8; ++i) {
    const int t1 = 2 * i + 1;
    const int tn0 = (2 * i + 2 < 16) ? 2 * i + 2 : 15;  // clamped dead-slot
    const int tn1 = (2 * i + 3 < 16) ? 2 * i + 3 : 15;  // stages keep counts
    bf16x8 afr[2][2], bfr[4][2];
    PHASE(0, 0, 1, 65536, rowbase, t1, 0)
    PHASE(0, 2, 0, 65536 + 16384, rowbase + 128, t1, 0)
    PHASE(0, 4, 0, 32768, colbase, tn0, 0)
    PHASE(0, 6, 0, 49152, colbase + 128, tn0, 1)
    PHASE(65536, 0, 1, 0, rowbase, tn0, 0)
    PHASE(65536, 2, 0, 16384, rowbase + 128, tn0, 0)
    PHASE(65536, 4, 0, 65536 + 32768, colbase, tn1, 0)
    PHASE(65536, 6, 0, 65536 + 49152, colbase + 128, tn1, 1)
  }

  // drain in-flight stages before repurposing LDS
  asm volatile("s_waitcnt vmcnt(0)" ::: "memory");
  __syncthreads();

  // ---- epilogue: masked exp row-sums + slot0 scatter ----
  int* yrow_s = (int*)lds;            // 256 ints
  int* ycol_s = (int*)(lds + 1024);   // 256 ints
  int* frow_s = (int*)(lds + 2048);   // 256 ints
  float* rsum = (float*)(lds + 4096); // 256*4 floats
  if (tid < 256) {
    yrow_s[tid] = y[rowbase + tid];
    frow_s[tid] = fpos[rowbase + tid];
  } else {
    ycol_s[tid - 256] = y[colbase + tid - 256];
  }
  __syncthreads();

  const int g = klo;
#pragma unroll
  for (int mf = 0; mf < 8; ++mf) {
    float rs[4] = {0.f, 0.f, 0.f, 0.f};
    int rloc[4], yr[4], fr[4];
#pragma unroll
    for (int reg = 0; reg < 4; ++reg) {
      rloc[reg] = wr * 128 + mf * 16 + g * 4 + reg;
      yr[reg] = yrow_s[rloc[reg]];
      fr[reg] = frow_s[rloc[reg]];
    }
#pragma unroll
    for (int nf = 0; nf < 4; ++nf) {
      int cl = wcn * 64 + nf * 16 + r0;
      int yc = ycol_s[cl];
      int gc = colbase + cl;
#pragma unroll
      for (int reg = 0; reg < 4; ++reg) {
        float sv = (acc[mf][nf][reg] + 1.0f) * 0.25f;
        float e = (yr[reg] == yc) ? 0.f : __expf(sv);
        rs[reg] += e;
        if (fr[reg] == gc) slot0[rowbase + rloc[reg]] = sv;
      }
    }
#pragma unroll
    for (int d = 1; d < 16; d <<= 1)
#pragma unroll
      for (int reg = 0; reg < 4; ++reg) rs[reg] += __shfl_xor(rs[reg], d);
    if (r0 == 0) {
#pragma unroll
      for (int reg = 0; reg < 4; ++reg)
        rsum[rloc[reg] * 4 + wcn] = rs[reg];
    }
  }
  __syncthreads();
  if (tid < 256)
    part[(size_t)cb * NR + rowbase + tid] =
        rsum[tid * 4] + rsum[tid * 4 + 1] + rsum[tid * 4 + 2] + rsum[tid * 4 + 3];
}

// ---- kernel 3: final loss reduction ----------------------------------------
__global__ __launch_bounds__(256) void k_final(const float* __restrict__ part,
                                               const float* __restrict__ slot0,
                                               const int* __restrict__ cnt,
                                               const int* __restrict__ y,
                                               const float* __restrict__ ce,
                                               float* __restrict__ out) {
  __shared__ float red[256];
  const int tid = threadIdx.x;
  const int r = blockIdx.x * 256 + tid;
  float S = 0.f;
#pragma unroll
  for (int b = 0; b < 16; ++b) S += part[(size_t)b * NR + r];
  float s0 = slot0[r];
  float zeros = 4094.0f + (float)cnt[y[r]];  // 8190 - (4096 - cnt)
  float cl = logf(__expf(s0) + S + zeros) - s0;
  red[tid] = 0.5f * (cl + ce[r]);
  __syncthreads();
  for (int s = 128; s > 0; s >>= 1) {
    if (tid < s) red[tid] += red[tid + s];
    __syncthreads();
  }
  if (tid == 0) atomicAdd(out, red[0] / (float)NR);
}

extern "C" void kernel_launch(void* const* d_in, const int* in_sizes, int n_in,
                              void* d_out, int out_size, void* d_ws, size_t ws_size,
                              hipStream_t stream) {
  const float* x = (const float*)d_in[0];
  const int* y = (const int*)d_in[1];
  const float* yp = (const float*)d_in[2];
  float* out = (float*)d_out;

  char* w = (char*)d_ws;
  unsigned short* xn = (unsigned short*)w;   // 8388608 B
  int* cnt = (int*)(w + 8388608);            // 2048 B
  int* fpos = (int*)(w + 8390656);           // 16384 B
  float* slot0 = (float*)(w + 8407040);      // 16384 B
  float* part = (float*)(w + 8423424);       // 16*4096*4 = 262144 B
  float* ce = (float*)(w + 8685568);         // 16384 B

  k_prep<<<2049, 256, 0, stream>>>(x, y, yp, xn, cnt, fpos, slot0, ce, out);
  k_gemm<<<256, 512, 0, stream>>>(xn, y, fpos, part, slot0);
  k_final<<<16, 256, 0, stream>>>(part, slot0, cnt, y, ce, out);
}

// Round 5
// 53.502 us; speedup vs baseline: 8.8680x; 1.0349x over previous
//
#include <hip/hip_runtime.h>
#include <hip/hip_bf16.h>

#define NR 4096
#define DIM 1024
#define NCLS 512

typedef __attribute__((ext_vector_type(4))) float f32x4;
typedef __attribute__((ext_vector_type(8))) short bf16x8;

static __device__ __forceinline__ unsigned short f2bf(float f) {
  __hip_bfloat16 h = __float2bfloat16(f);
  return *reinterpret_cast<unsigned short*>(&h);
}

// ---- kernel 1: fused prep -------------------------------------------------
// blocks 0..1023   : row norms -> bf16 normalized copy (4 rows/block)
// blocks 1024..2047: CE per row (4 rows/block)
// block 2048       : label stats (cnt, fpos via min1/min2), zero slot0, zero out
__global__ __launch_bounds__(256) void k_prep(const float* __restrict__ x,
                                              const int* __restrict__ y,
                                              const float* __restrict__ yp,
                                              unsigned short* __restrict__ xn,
                                              int* __restrict__ cnt,
                                              int* __restrict__ fpos,
                                              float* __restrict__ slot0,
                                              float* __restrict__ ce,
                                              float* __restrict__ out) {
  const int b = blockIdx.x;
  const int tid = threadIdx.x;
  if (b < 1024) {
    int row = b * 4 + (tid >> 6);
    int lane = tid & 63;
    const float4* xr = reinterpret_cast<const float4*>(x + (size_t)row * DIM);
    float4 v[4];
    float s = 0.f;
#pragma unroll
    for (int it = 0; it < 4; ++it) {
      v[it] = xr[it * 64 + lane];
      s += v[it].x * v[it].x + v[it].y * v[it].y + v[it].z * v[it].z + v[it].w * v[it].w;
    }
#pragma unroll
    for (int d = 1; d < 64; d <<= 1) s += __shfl_xor(s, d);
    float inv = 1.0f / fmaxf(sqrtf(s), 1e-8f);
    ushort4* xo = reinterpret_cast<ushort4*>(xn + (size_t)row * DIM);
#pragma unroll
    for (int it = 0; it < 4; ++it) {
      ushort4 u;
      u.x = f2bf(v[it].x * inv);
      u.y = f2bf(v[it].y * inv);
      u.z = f2bf(v[it].z * inv);
      u.w = f2bf(v[it].w * inv);
      xo[it * 64 + lane] = u;
    }
  } else if (b < 2048) {
    int row = (b - 1024) * 4 + (tid >> 6);
    int lane = tid & 63;
    const float4* p = reinterpret_cast<const float4*>(yp + (size_t)row * NCLS);
    float4 v0 = p[lane], v1 = p[lane + 64];
    float m = fmaxf(fmaxf(fmaxf(v0.x, v0.y), fmaxf(v0.z, v0.w)),
                    fmaxf(fmaxf(v1.x, v1.y), fmaxf(v1.z, v1.w)));
#pragma unroll
    for (int d = 1; d < 64; d <<= 1) m = fmaxf(m, __shfl_xor(m, d));
    float s = __expf(v0.x - m) + __expf(v0.y - m) + __expf(v0.z - m) + __expf(v0.w - m) +
              __expf(v1.x - m) + __expf(v1.y - m) + __expf(v1.z - m) + __expf(v1.w - m);
#pragma unroll
    for (int d = 1; d < 64; d <<= 1) s += __shfl_xor(s, d);
    if (lane == 0) {
      float py = yp[(size_t)row * NCLS + y[row]];
      ce[row] = logf(s) + m - py;
    }
  } else {
    __shared__ int ys[NR];
    __shared__ int scnt[NCLS], sm1[NCLS], sm2[NCLS];
    for (int j = tid; j < NR; j += 256) ys[j] = y[j];
    for (int c = tid; c < NCLS; c += 256) { scnt[c] = 0; sm1[c] = NR; sm2[c] = NR; }
    __syncthreads();
    for (int i = tid; i < NR; i += 256) {
      int c = ys[i];
      atomicAdd(&scnt[c], 1);
      atomicMin(&sm1[c], i);
    }
    __syncthreads();
    for (int i = tid; i < NR; i += 256) {
      int c = ys[i];
      if (sm1[c] != i) atomicMin(&sm2[c], i);
    }
    __syncthreads();
    for (int i = tid; i < NR; i += 256) {
      int c = ys[i];
      int m1 = sm1[c];
      int j = (m1 == i) ? ((sm2[c] >= NR) ? -1 : sm2[c]) : m1;
      fpos[i] = j;
      slot0[i] = 0.f;
    }
    for (int c = tid; c < NCLS; c += 256) cnt[c] = scnt[c];
    if (tid == 0) out[0] = 0.f;
  }
}

// ---- kernel 2: 8-phase 256x256 bf16 MFMA GEMM + fused masked-exp epilogue --
// LDS: 2 bufs x {A0,A1,B0,B1} 16KB half-tiles (128 rows x 64 bf16), 128KB.
// Bank swizzle (conflict-free for this access pattern): within a half-tile,
//   phys = logical ^ ((row & 7) << 4)      (row = byte>>7; involution)
// Applied as inverse-swizzled GLOBAL source for global_load_lds (dest linear)
// and swizzled ds_read addresses. Wave slot index = (kk*4+klo) ^ (r0&7):
// all 32 banks busy, exactly 2 lanes/bank (free).
// Stage schedule (iter i, t0=2i, t1=2i+1): ph0:A0(t1) ph1:A1(t1)
// ph2:B0(t0+2) ph3:B1(t0+2)[vmcnt4] ph4:A0(t0+2) ph5:A1(t0+2)
// ph6:B0(t1+2) ph7:B1(t1+2)[vmcnt4].

#define STAGE(SSLOT, GROWBASE, KT)                                               \
  _Pragma("unroll") for (int q = 0; q < 2; ++q) {                                \
    const char* _src = (const char*)xn +                                         \
        (size_t)((GROWBASE) + srow[q]) * 2048 + (size_t)(KT) * 128 + scolb[q];   \
    __builtin_amdgcn_global_load_lds(                                            \
        (const __attribute__((address_space(1))) void*)_src,                     \
        (__attribute__((address_space(3))) void*)(lds + (SSLOT) + q * 8192 +     \
                                                  (w << 10)),                    \
        16, 0, 0);                                                               \
  }

#define PHASE(BUFB, MF0, LOADB, SSLOT, SBASE, SKT, VM)                           \
  {                                                                              \
    _Pragma("unroll") for (int mm = 0; mm < 2; ++mm)                             \
      _Pragma("unroll") for (int kk = 0; kk < 2; ++kk)                           \
        afr[mm][kk] = *(const bf16x8*)(lds + (BUFB) + ABaseW +                   \
                                       ((MF0) + mm) * 2048 +                     \
                                       ((kk * 64 + klo16) ^ rswz));              \
    if (LOADB) {                                                                 \
      _Pragma("unroll") for (int nf = 0; nf < 4; ++nf)                           \
        _Pragma("unroll") for (int kk = 0; kk < 2; ++kk)                         \
          bfr[nf][kk] = *(const bf16x8*)(lds + (BUFB) + BBaseW +                 \
                                         nf * 2048 +                             \
                                         ((kk * 64 + klo16) ^ rswz));            \
    }                                                                            \
    STAGE(SSLOT, SBASE, SKT)                                                     \
    if (VM) asm volatile("s_waitcnt vmcnt(4)" ::: "memory");                     \
    __builtin_amdgcn_s_barrier();                                                \
    asm volatile("s_waitcnt lgkmcnt(0)" ::: "memory");                           \
    __builtin_amdgcn_sched_barrier(0);                                           \
    __builtin_amdgcn_s_setprio(1);                                               \
    _Pragma("unroll") for (int kk = 0; kk < 2; ++kk)                             \
      _Pragma("unroll") for (int mm = 0; mm < 2; ++mm)                           \
        _Pragma("unroll") for (int nf = 0; nf < 4; ++nf)                         \
          acc[(MF0) + mm][nf] = __builtin_amdgcn_mfma_f32_16x16x32_bf16(         \
              afr[mm][kk], bfr[nf][kk], acc[(MF0) + mm][nf], 0, 0, 0);           \
    __builtin_amdgcn_s_setprio(0);                                               \
    __builtin_amdgcn_sched_barrier(0);                                           \
    __builtin_amdgcn_s_barrier();                                                \
  }

__global__ __launch_bounds__(512, 2) void k_gemm(const unsigned short* __restrict__ xn,
                                                 const int* __restrict__ y,
                                                 const int* __restrict__ fpos,
                                                 float* __restrict__ part,
                                                 float* __restrict__ slot0) {
  __shared__ char lds[131072];
  const int tid = threadIdx.x;
  const int w = tid >> 6, lane = tid & 63;
  const int wr = w >> 2, wcn = w & 3;
  const int r0 = lane & 15, klo = lane >> 4;

  const int bid = blockIdx.x;
  const int swzb = (bid & 7) * 32 + (bid >> 3);  // XCD swizzle, 256%8==0 ok
  const int rb = swzb >> 4, cb = swzb & 15;
  const int rowbase = rb * 256, colbase = cb * 256;

  const int klo16 = klo * 16;
  const int rswz = (r0 & 7) << 4;
  const int ABaseW = wr * 16384 + r0 * 128;
  const int BBaseW = 32768 + (wcn >> 1) * 16384 + (wcn & 1) * 8192 + r0 * 128;

  int srow[2], scolb[2];
#pragma unroll
  for (int q = 0; q < 2; ++q) {
    int D = q * 8192 + tid * 16;                 // linear dest in half-tile
    int L = D ^ (((D >> 7) & 7) << 4);           // inverse swizzle (involution)
    srow[q] = L >> 7;
    scolb[q] = L & 127;
  }

  f32x4 acc[8][4] = {};

  // prologue: K-tile 0 -> buf0 fully; B halves of K-tile 1 -> buf1
  STAGE(0, rowbase, 0)
  STAGE(16384, rowbase + 128, 0)
  STAGE(32768, colbase, 0)
  STAGE(49152, colbase + 128, 0)
  STAGE(65536 + 32768, colbase, 1)
  STAGE(65536 + 49152, colbase + 128, 1)
  asm volatile("s_waitcnt vmcnt(4)" ::: "memory");
  __builtin_amdgcn_s_barrier();

  for (int i = 0; i < 8; ++i) {
    const int t1 = 2 * i + 1;
    const int tn0 = (2 * i + 2 < 16) ? 2 * i + 2 : 15;  // clamped dead-slot
    const int tn1 = (2 * i + 3 < 16) ? 2 * i + 3 : 15;  // stages keep counts
    bf16x8 afr[2][2], bfr[4][2];
    PHASE(0, 0, 1, 65536, rowbase, t1, 0)
    PHASE(0, 2, 0, 65536 + 16384, rowbase + 128, t1, 0)
    PHASE(0, 4, 0, 32768, colbase, tn0, 0)
    PHASE(0, 6, 0, 49152, colbase + 128, tn0, 1)
    PHASE(65536, 0, 1, 0, rowbase, tn0, 0)
    PHASE(65536, 2, 0, 16384, rowbase + 128, tn0, 0)
    PHASE(65536, 4, 0, 65536 + 32768, colbase, tn1, 0)
    PHASE(65536, 6, 0, 65536 + 49152, colbase + 128, tn1, 1)
  }

  // drain in-flight stages before repurposing LDS
  asm volatile("s_waitcnt vmcnt(0)" ::: "memory");
  __syncthreads();

  // ---- epilogue: masked exp row-sums + slot0 scatter ----
  int* yrow_s = (int*)lds;            // 256 ints
  int* ycol_s = (int*)(lds + 1024);   // 256 ints
  int* frow_s = (int*)(lds + 2048);   // 256 ints
  float* rsum = (float*)(lds + 4096); // 256*4 floats
  if (tid < 256) {
    yrow_s[tid] = y[rowbase + tid];
    frow_s[tid] = fpos[rowbase + tid];
  } else {
    ycol_s[tid - 256] = y[colbase + tid - 256];
  }
  __syncthreads();

  const int g = klo;
#pragma unroll
  for (int mf = 0; mf < 8; ++mf) {
    float rs[4] = {0.f, 0.f, 0.f, 0.f};
    int rloc[4], yr[4], fr[4];
#pragma unroll
    for (int reg = 0; reg < 4; ++reg) {
      rloc[reg] = wr * 128 + mf * 16 + g * 4 + reg;
      yr[reg] = yrow_s[rloc[reg]];
      fr[reg] = frow_s[rloc[reg]];
    }
#pragma unroll
    for (int nf = 0; nf < 4; ++nf) {
      int cl = wcn * 64 + nf * 16 + r0;
      int yc = ycol_s[cl];
      int gc = colbase + cl;
#pragma unroll
      for (int reg = 0; reg < 4; ++reg) {
        float sv = (acc[mf][nf][reg] + 1.0f) * 0.25f;
        float e = (yr[reg] == yc) ? 0.f : __expf(sv);
        rs[reg] += e;
        if (fr[reg] == gc) slot0[rowbase + rloc[reg]] = sv;
      }
    }
#pragma unroll
    for (int d = 1; d < 16; d <<= 1)
#pragma unroll
      for (int reg = 0; reg < 4; ++reg) rs[reg] += __shfl_xor(rs[reg], d);
    if (r0 == 0) {
#pragma unroll
      for (int reg = 0; reg < 4; ++reg)
        rsum[rloc[reg] * 4 + wcn] = rs[reg];
    }
  }
  __syncthreads();
  if (tid < 256)
    part[(size_t)cb * NR + rowbase + tid] =
        rsum[tid * 4] + rsum[tid * 4 + 1] + rsum[tid * 4 + 2] + rsum[tid * 4 + 3];
}

// ---- kernel 3: final loss reduction ----------------------------------------
__global__ __launch_bounds__(256) void k_final(const float* __restrict__ part,
                                               const float* __restrict__ slot0,
                                               const int* __restrict__ cnt,
                                               const int* __restrict__ y,
                                               const float* __restrict__ ce,
                                               float* __restrict__ out) {
  __shared__ float red[256];
  const int tid = threadIdx.x;
  const int r = blockIdx.x * 256 + tid;
  float S = 0.f;
#pragma unroll
  for (int b = 0; b < 16; ++b) S += part[(size_t)b * NR + r];
  float s0 = slot0[r];
  float zeros = 4094.0f + (float)cnt[y[r]];  // 8190 - (4096 - cnt)
  float cl = logf(__expf(s0) + S + zeros) - s0;
  red[tid] = 0.5f * (cl + ce[r]);
  __syncthreads();
  for (int s = 128; s > 0; s >>= 1) {
    if (tid < s) red[tid] += red[tid + s];
    __syncthreads();
  }
  if (tid == 0) atomicAdd(out, red[0] / (float)NR);
}

extern "C" void kernel_launch(void* const* d_in, const int* in_sizes, int n_in,
                              void* d_out, int out_size, void* d_ws, size_t ws_size,
                              hipStream_t stream) {
  const float* x = (const float*)d_in[0];
  const int* y = (const int*)d_in[1];
  const float* yp = (const float*)d_in[2];
  float* out = (float*)d_out;

  char* w = (char*)d_ws;
  unsigned short* xn = (unsigned short*)w;   // 8388608 B
  int* cnt = (int*)(w + 8388608);            // 2048 B
  int* fpos = (int*)(w + 8390656);           // 16384 B
  float* slot0 = (float*)(w + 8407040);      // 16384 B
  float* part = (float*)(w + 8423424);       // 16*4096*4 = 262144 B
  float* ce = (float*)(w + 8685568);         // 16384 B

  k_prep<<<2049, 256, 0, stream>>>(x, y, yp, xn, cnt, fpos, slot0, ce, out);
  k_gemm<<<256, 512, 0, stream>>>(xn, y, fpos, part, slot0);
  k_final<<<16, 256, 0, stream>>>(part, slot0, cnt, y, ce, out);
}

// Round 6
// 49.096 us; speedup vs baseline: 9.6639x; 1.0898x over previous
//
#include <hip/hip_runtime.h>
#include <hip/hip_bf16.h>
#include <hip/hip_fp8.h>

#define NR 4096
#define DIM 1024
#define NCLS 512

typedef __attribute__((ext_vector_type(4))) float f32x4;
typedef __attribute__((ext_vector_type(2))) long i64x2;

// ---- kernel 1: fused prep -------------------------------------------------
// blocks 0..1023   : row norms -> fp8 e4m3 normalized copy (x64), k-interleaved
// blocks 1024..2047: CE per row (4 rows/block)
// block 2048       : label stats (cnt, fpos via min1/min2), zero slot0/out
// fp8 layout per row: 16 K-tiles of 64 B; within a K-tile byte p holds
// element k = (p>>3 & 1)*32 + (p>>4)*8 + (p&7)   (so one 16B chunk at
// p=klo*16 is exactly the MFMA fragment pair {kk0,kk1} for lane group klo).
__global__ __launch_bounds__(256) void k_prep(const float* __restrict__ x,
                                              const int* __restrict__ y,
                                              const float* __restrict__ yp,
                                              unsigned char* __restrict__ xnp,
                                              int* __restrict__ cnt,
                                              int* __restrict__ fpos,
                                              float* __restrict__ slot0,
                                              float* __restrict__ ce,
                                              float* __restrict__ out) {
  const int b = blockIdx.x;
  const int tid = threadIdx.x;
  if (b < 1024) {
    int row = b * 4 + (tid >> 6);
    int lane = tid & 63;
    const float4* xr = reinterpret_cast<const float4*>(x + (size_t)row * DIM);
    float4 v[4];
    float s = 0.f;
#pragma unroll
    for (int it = 0; it < 4; ++it) {
      v[it] = xr[it * 64 + lane];
      s += v[it].x * v[it].x + v[it].y * v[it].y + v[it].z * v[it].z + v[it].w * v[it].w;
    }
#pragma unroll
    for (int d = 1; d < 64; d <<= 1) s += __shfl_xor(s, d);
    float inv = 64.0f / fmaxf(sqrtf(s), 1e-8f);  // fold SCALE=64 (exact pow2)
    unsigned char* xo = xnp + (size_t)row * DIM;
#pragma unroll
    for (int it = 0; it < 4; ++it) {
      int k0q = it * 64 + lane;          // quad index (4 elems per quad)
      int kt = k0q >> 4;                 // K-tile
      int r6 = (k0q & 15) * 4;           // k within K-tile (0..60, step 4)
      int p = ((r6 & 31) >> 3) * 16 + (r6 >> 5) * 8 + (r6 & 7);
      __hip_fp8_e4m3 b0(v[it].x * inv), b1(v[it].y * inv),
                     b2(v[it].z * inv), b3(v[it].w * inv);
      unsigned int pk = (unsigned int)b0.__x | ((unsigned int)b1.__x << 8) |
                        ((unsigned int)b2.__x << 16) | ((unsigned int)b3.__x << 24);
      *(unsigned int*)(xo + kt * 64 + p) = pk;
    }
  } else if (b < 2048) {
    int row = (b - 1024) * 4 + (tid >> 6);
    int lane = tid & 63;
    const float4* p = reinterpret_cast<const float4*>(yp + (size_t)row * NCLS);
    float4 v0 = p[lane], v1 = p[lane + 64];
    float m = fmaxf(fmaxf(fmaxf(v0.x, v0.y), fmaxf(v0.z, v0.w)),
                    fmaxf(fmaxf(v1.x, v1.y), fmaxf(v1.z, v1.w)));
#pragma unroll
    for (int d = 1; d < 64; d <<= 1) m = fmaxf(m, __shfl_xor(m, d));
    float s = __expf(v0.x - m) + __expf(v0.y - m) + __expf(v0.z - m) + __expf(v0.w - m) +
              __expf(v1.x - m) + __expf(v1.y - m) + __expf(v1.z - m) + __expf(v1.w - m);
#pragma unroll
    for (int d = 1; d < 64; d <<= 1) s += __shfl_xor(s, d);
    if (lane == 0) {
      float py = yp[(size_t)row * NCLS + y[row]];
      ce[row] = logf(s) + m - py;
    }
  } else {
    __shared__ int ys[NR];
    __shared__ int scnt[NCLS], sm1[NCLS], sm2[NCLS];
    for (int j = tid; j < NR; j += 256) ys[j] = y[j];
    for (int c = tid; c < NCLS; c += 256) { scnt[c] = 0; sm1[c] = NR; sm2[c] = NR; }
    __syncthreads();
    for (int i = tid; i < NR; i += 256) {
      int c = ys[i];
      atomicAdd(&scnt[c], 1);
      atomicMin(&sm1[c], i);
    }
    __syncthreads();
    for (int i = tid; i < NR; i += 256) {
      int c = ys[i];
      if (sm1[c] != i) atomicMin(&sm2[c], i);
    }
    __syncthreads();
    for (int i = tid; i < NR; i += 256) {
      int c = ys[i];
      int m1 = sm1[c];
      int j = (m1 == i) ? ((sm2[c] >= NR) ? -1 : sm2[c]) : m1;
      fpos[i] = j;
      slot0[i] = 0.f;
    }
    for (int c = tid; c < NCLS; c += 256) cnt[c] = scnt[c];
    if (tid == 0) out[0] = 0.f;
  }
}

// ---- kernel 2: 8-phase 256x256 fp8 MFMA GEMM + fused masked-exp epilogue ---
// LDS: 2 bufs x {A0,A1,B0,B1} 8KB half-tiles (128 rows x 64 fp8), 64KB total.
// Bank swizzle: phys = logical ^ ((row & 3) << 4) within a half-tile
// (row = byte>>6; involution). Dest linear for global_load_lds; source
// pre-inverse-swizzled; ds_read swizzled. Wave slot = klo ^ (r0&3):
// 64 lanes -> 64 distinct 16B chunks of 1KB -> conflict-free.
// One b128 = fragment pair {kk0,kk1} thanks to the k-interleaved row layout.
// Stage = 1 global_load_lds (512 thr x 16B = 8KB half-tile).
// Schedule (iter i, t0=2i, t1=2i+1): ph0:A0(t1)->b1 ph1:A1(t1)->b1
// ph2:B0(t0+2)->b0 ph3:B1(t0+2)->b0 [vmcnt2] ph4:A0(t0+2)->b0
// ph5:A1(t0+2)->b0 ph6:B0(t1+2)->b1 ph7:B1(t1+2)->b1 [vmcnt2].

#define STAGE(SSLOT, GROWBASE, KT)                                               \
  {                                                                              \
    const char* _src = (const char*)xnp +                                        \
        (size_t)((GROWBASE) + srow) * 1024 + (size_t)(KT) * 64 + scol;           \
    __builtin_amdgcn_global_load_lds(                                            \
        (const __attribute__((address_space(1))) void*)_src,                     \
        (__attribute__((address_space(3))) void*)(lds + (SSLOT) + (w << 10)),    \
        16, 0, 0);                                                               \
  }

#define PHASE(BUFB, MF0, LOADB, SSLOT, SBASE, SKT, VM)                           \
  {                                                                              \
    _Pragma("unroll") for (int mm = 0; mm < 2; ++mm)                             \
      afr[mm] = *(const i64x2*)(lds + (BUFB) + ABaseW +                          \
                                ((MF0) + mm) * 1024 + kread);                    \
    if (LOADB) {                                                                 \
      _Pragma("unroll") for (int nf = 0; nf < 4; ++nf)                           \
        bfr[nf] = *(const i64x2*)(lds + (BUFB) + BBaseW + nf * 1024 + kread);    \
    }                                                                            \
    STAGE(SSLOT, SBASE, SKT)                                                     \
    if (VM) asm volatile("s_waitcnt vmcnt(2)" ::: "memory");                     \
    __builtin_amdgcn_s_barrier();                                                \
    asm volatile("s_waitcnt lgkmcnt(0)" ::: "memory");                           \
    __builtin_amdgcn_sched_barrier(0);                                           \
    __builtin_amdgcn_s_setprio(1);                                               \
    _Pragma("unroll") for (int kk = 0; kk < 2; ++kk)                             \
      _Pragma("unroll") for (int mm = 0; mm < 2; ++mm)                           \
        _Pragma("unroll") for (int nf = 0; nf < 4; ++nf)                         \
          acc[(MF0) + mm][nf] = __builtin_amdgcn_mfma_f32_16x16x32_fp8_fp8(      \
              afr[mm][kk], bfr[nf][kk], acc[(MF0) + mm][nf], 0, 0, 0);           \
    __builtin_amdgcn_s_setprio(0);                                               \
    __builtin_amdgcn_sched_barrier(0);                                           \
    __builtin_amdgcn_s_barrier();                                                \
  }

__global__ __launch_bounds__(512, 2) void k_gemm(const unsigned char* __restrict__ xnp,
                                                 const int* __restrict__ y,
                                                 const int* __restrict__ fpos,
                                                 float* __restrict__ part,
                                                 float* __restrict__ slot0) {
  __shared__ char lds[65536];
  const int tid = threadIdx.x;
  const int w = tid >> 6, lane = tid & 63;
  const int wr = w >> 2, wcn = w & 3;
  const int r0 = lane & 15, klo = lane >> 4;

  const int bid = blockIdx.x;
  const int swzb = (bid & 7) * 32 + (bid >> 3);  // XCD swizzle, 256%8==0 ok
  const int rb = swzb >> 4, cb = swzb & 15;
  const int rowbase = rb * 256, colbase = cb * 256;

  const int kread = (klo * 16) ^ ((r0 & 3) << 4);
  const int ABaseW = wr * 8192 + r0 * 64;
  const int BBaseW = 16384 + (wcn >> 1) * 8192 + (wcn & 1) * 4096 + r0 * 64;

  int srow, scol;
  {
    int D = tid * 16;                          // linear dest in half-tile
    int L = D ^ (((D >> 6) & 3) << 4);         // inverse swizzle (involution)
    srow = L >> 6;
    scol = L & 63;
  }

  f32x4 acc[8][4] = {};

  // prologue: K-tile 0 -> buf0 fully; B halves of K-tile 1 -> buf1
  STAGE(0, rowbase, 0)
  STAGE(8192, rowbase + 128, 0)
  STAGE(16384, colbase, 0)
  STAGE(24576, colbase + 128, 0)
  STAGE(32768 + 16384, colbase, 1)
  STAGE(32768 + 24576, colbase + 128, 1)
  asm volatile("s_waitcnt vmcnt(2)" ::: "memory");
  __builtin_amdgcn_s_barrier();

  for (int i = 0; i < 8; ++i) {
    const int t1 = 2 * i + 1;
    const int tn0 = (2 * i + 2 < 16) ? 2 * i + 2 : 15;  // clamped dead-slot
    const int tn1 = (2 * i + 3 < 16) ? 2 * i + 3 : 15;  // stages keep counts
    i64x2 afr[2], bfr[4];
    PHASE(0, 0, 1, 32768, rowbase, t1, 0)
    PHASE(0, 2, 0, 32768 + 8192, rowbase + 128, t1, 0)
    PHASE(0, 4, 0, 16384, colbase, tn0, 0)
    PHASE(0, 6, 0, 24576, colbase + 128, tn0, 1)
    PHASE(32768, 0, 1, 0, rowbase, tn0, 0)
    PHASE(32768, 2, 0, 8192, rowbase + 128, tn0, 0)
    PHASE(32768, 4, 0, 32768 + 16384, colbase, tn1, 0)
    PHASE(32768, 6, 0, 32768 + 24576, colbase + 128, tn1, 1)
  }

  // drain in-flight stages before repurposing LDS
  asm volatile("s_waitcnt vmcnt(0)" ::: "memory");
  __syncthreads();

  // ---- epilogue: masked exp row-sums + slot0 scatter ----
  // sim = acc/4096 (SCALE=64 squared), sv = (sim+1)*0.25 = acc/16384 + 0.25
  int* yrow_s = (int*)lds;            // 256 ints
  int* ycol_s = (int*)(lds + 1024);   // 256 ints
  int* frow_s = (int*)(lds + 2048);   // 256 ints
  float* rsum = (float*)(lds + 4096); // 256*4 floats
  if (tid < 256) {
    yrow_s[tid] = y[rowbase + tid];
    frow_s[tid] = fpos[rowbase + tid];
  } else {
    ycol_s[tid - 256] = y[colbase + tid - 256];
  }
  __syncthreads();

  const int g = klo;
#pragma unroll
  for (int mf = 0; mf < 8; ++mf) {
    float rs[4] = {0.f, 0.f, 0.f, 0.f};
    int rloc[4], yr[4], fr[4];
#pragma unroll
    for (int reg = 0; reg < 4; ++reg) {
      rloc[reg] = wr * 128 + mf * 16 + g * 4 + reg;
      yr[reg] = yrow_s[rloc[reg]];
      fr[reg] = frow_s[rloc[reg]];
    }
#pragma unroll
    for (int nf = 0; nf < 4; ++nf) {
      int cl = wcn * 64 + nf * 16 + r0;
      int yc = ycol_s[cl];
      int gc = colbase + cl;
#pragma unroll
      for (int reg = 0; reg < 4; ++reg) {
        float sv = acc[mf][nf][reg] * (1.0f / 16384.f) + 0.25f;
        float e = (yr[reg] == yc) ? 0.f : __expf(sv);
        rs[reg] += e;
        if (fr[reg] == gc) slot0[rowbase + rloc[reg]] = sv;
      }
    }
#pragma unroll
    for (int d = 1; d < 16; d <<= 1)
#pragma unroll
      for (int reg = 0; reg < 4; ++reg) rs[reg] += __shfl_xor(rs[reg], d);
    if (r0 == 0) {
#pragma unroll
      for (int reg = 0; reg < 4; ++reg)
        rsum[rloc[reg] * 4 + wcn] = rs[reg];
    }
  }
  __syncthreads();
  if (tid < 256)
    part[(size_t)cb * NR + rowbase + tid] =
        rsum[tid * 4] + rsum[tid * 4 + 1] + rsum[tid * 4 + 2] + rsum[tid * 4 + 3];
}

// ---- kernel 3: final loss reduction ----------------------------------------
__global__ __launch_bounds__(256) void k_final(const float* __restrict__ part,
                                               const float* __restrict__ slot0,
                                               const int* __restrict__ cnt,
                                               const int* __restrict__ y,
                                               const float* __restrict__ ce,
                                               float* __restrict__ out) {
  __shared__ float red[256];
  const int tid = threadIdx.x;
  const int r = blockIdx.x * 256 + tid;
  float S = 0.f;
#pragma unroll
  for (int b = 0; b < 16; ++b) S += part[(size_t)b * NR + r];
  float s0 = slot0[r];
  float zeros = 4094.0f + (float)cnt[y[r]];  // 8190 - (4096 - cnt)
  float cl = logf(__expf(s0) + S + zeros) - s0;
  red[tid] = 0.5f * (cl + ce[r]);
  __syncthreads();
  for (int s = 128; s > 0; s >>= 1) {
    if (tid < s) red[tid] += red[tid + s];
    __syncthreads();
  }
  if (tid == 0) atomicAdd(out, red[0] / (float)NR);
}

extern "C" void kernel_launch(void* const* d_in, const int* in_sizes, int n_in,
                              void* d_out, int out_size, void* d_ws, size_t ws_size,
                              hipStream_t stream) {
  const float* x = (const float*)d_in[0];
  const int* y = (const int*)d_in[1];
  const float* yp = (const float*)d_in[2];
  float* out = (float*)d_out;

  char* w = (char*)d_ws;
  unsigned char* xnp = (unsigned char*)w;    // 4096*1024 = 4194304 B
  int* cnt = (int*)(w + 4194304);            // 2048 B
  int* fpos = (int*)(w + 4196352);           // 16384 B
  float* slot0 = (float*)(w + 4212736);      // 16384 B
  float* part = (float*)(w + 4229120);       // 16*4096*4 = 262144 B
  float* ce = (float*)(w + 4491264);         // 16384 B

  k_prep<<<2049, 256, 0, stream>>>(x, y, yp, xnp, cnt, fpos, slot0, ce, out);
  k_gemm<<<256, 512, 0, stream>>>(xnp, y, fpos, part, slot0);
  k_final<<<16, 256, 0, stream>>>(part, slot0, cnt, y, ce, out);
}